// Round 3
// baseline (498.115 us; speedup 1.0000x reference)
//
#include <hip/hip_runtime.h>
#include <stdint.h>

typedef unsigned short u16;
typedef __attribute__((ext_vector_type(8))) __bf16 bf16x8;
typedef __attribute__((ext_vector_type(4))) float f32x4;

#define SEQ 2048
#define EMB 768
#define NB  8

__device__ __forceinline__ u16 f2bf(float f) {
  union { float f; uint32_t u; } a; a.f = f;
  uint32_t r = a.u + 0x7fffu + ((a.u >> 16) & 1u);
  return (u16)(r >> 16);
}
__device__ __forceinline__ float bf2f(u16 h) {
  union { uint32_t u; float f; } a; a.u = ((uint32_t)h) << 16;
  return a.f;
}

// ---------------------------------------------------------------------------
// dtype detector: samples even-index u16s of x. fp32 data -> low mantissa
// halves -> uniform exponent field -> ~37% land in [160,254]. bf16 N(0,1)
// data -> exponents <= ~130 -> ~0%. Writes flag (1 = fp32 inputs).
// ---------------------------------------------------------------------------
__global__ __launch_bounds__(256) void k_detect(const u16* __restrict__ x,
                                                int* __restrict__ flag)
{
  const int tid = threadIdx.x;
  int bad = 0;
#pragma unroll
  for (int i = 0; i < 4; ++i) {
    const u16 h = x[(tid * 4 + i) * 2];
    const int e = (h >> 7) & 0xFF;
    bad += (e >= 160 && e <= 254) ? 1 : 0;
  }
#pragma unroll
  for (int off = 32; off > 0; off >>= 1) bad += __shfl_down(bad, off);
  __shared__ int cnt[4];
  if ((tid & 63) == 0) cnt[tid >> 6] = bad;
  __syncthreads();
  if (tid == 0) *flag = (cnt[0] + cnt[1] + cnt[2] + cnt[3] > 200) ? 1 : 0;
}

// x -> canonical bf16 buffer (4 elements/thread)
__global__ __launch_bounds__(256) void k_convert_x(
    const void* __restrict__ src, u16* __restrict__ dst,
    const int* __restrict__ flag, int n4)
{
  const int i = blockIdx.x * 256 + threadIdx.x;
  if (i >= n4) return;
  if (*flag) {
    const float4 f = ((const float4*)src)[i];
    ushort4 o;
    o.x = f2bf(f.x); o.y = f2bf(f.y); o.z = f2bf(f.z); o.w = f2bf(f.w);
    ((ushort4*)dst)[i] = o;
  } else {
    ((ushort4*)dst)[i] = ((const ushort4*)src)[i];
  }
}

// biases -> fp32 buffer [4][768]
__global__ __launch_bounds__(256) void k_convert_bias(
    const void* __restrict__ b0, const void* __restrict__ b1,
    const void* __restrict__ b2, const void* __restrict__ b3,
    float* __restrict__ dst, const int* __restrict__ flag)
{
  const int z = blockIdx.x;
  const void* src = (z == 0) ? b0 : (z == 1) ? b1 : (z == 2) ? b2 : b3;
  const int f32 = *flag;
#pragma unroll
  for (int i = 0; i < 3; ++i) {
    const int j = threadIdx.x + i * 256;
    const float v = f32 ? ((const float*)src)[j] : bf2f(((const u16*)src)[j]);
    dst[z * EMB + j] = v;
  }
}

// weights: convert + transpose -> WT (bf16, [4][768][768])
__global__ __launch_bounds__(256) void k_transpose_w(
    const void* __restrict__ W0, const void* __restrict__ W1,
    const void* __restrict__ W2, const void* __restrict__ W3,
    u16* __restrict__ WT, const int* __restrict__ flag)
{
  __shared__ u16 t[32][33];
  const int z = blockIdx.z;
  const void* in = (z == 0) ? W0 : (z == 1) ? W1 : (z == 2) ? W2 : W3;
  u16* out = WT + (size_t)z * EMB * EMB;
  const int c0 = blockIdx.x * 32, r0 = blockIdx.y * 32;
  const int tx = threadIdx.x, ty = threadIdx.y;
  const int f32 = *flag;
#pragma unroll
  for (int i = 0; i < 4; ++i) {
    const size_t idx = (size_t)(r0 + ty + i * 8) * EMB + c0 + tx;
    t[ty + i * 8][tx] = f32 ? f2bf(((const float*)in)[idx])
                            : ((const u16*)in)[idx];
  }
  __syncthreads();
#pragma unroll
  for (int i = 0; i < 4; ++i)
    out[(size_t)(c0 + ty + i * 8) * EMB + r0 + tx] = t[tx][ty + i * 8];
}

// ---------------------------------------------------------------------------
// 128x128 MFMA GEMM tile: C[m,n] = sum_k A[m,k] * BT[n,k]
// A, BT row-major bf16. 256 threads = 4 waves, each 64x64 (4x4 MFMA tiles).
// BK=32, register staging. EPI: 0 = bias add, output bf16 or fp32 per of32;
// 1 = f32 out * scale; 2 = bf16 out.
// ---------------------------------------------------------------------------
template <int EPI>
__device__ __forceinline__ void gemm_core(
    const u16* __restrict__ A, int lda,
    const u16* __restrict__ BT, int ldbt,
    void* __restrict__ Cp, int ldc,
    const float* __restrict__ biasf, const int* __restrict__ of32,
    float scale, int K, int m0, int n0)
{
  __shared__ __align__(16) u16 As[128 * 32];
  __shared__ __align__(16) u16 Bs[128 * 32];
  const int tid  = threadIdx.x;
  const int lane = tid & 63;
  const int wave = tid >> 6;
  const int wr   = (wave >> 1) * 64;
  const int wc   = (wave & 1) * 64;
  const int lrow = lane & 15;
  const int quad = lane >> 4;

  const int c0 = tid, c1 = tid + 256;
  const int r0_ = c0 >> 2, s0_ = c0 & 3;
  const int r1_ = c1 >> 2, s1_ = c1 & 3;
  const u16* gA0 = A  + (size_t)(m0 + r0_) * lda  + s0_ * 8;
  const u16* gA1 = A  + (size_t)(m0 + r1_) * lda  + s1_ * 8;
  const u16* gB0 = BT + (size_t)(n0 + r0_) * ldbt + s0_ * 8;
  const u16* gB1 = BT + (size_t)(n0 + r1_) * ldbt + s1_ * 8;

  f32x4 acc[4][4];
#pragma unroll
  for (int i = 0; i < 4; ++i)
#pragma unroll
    for (int j = 0; j < 4; ++j)
#pragma unroll
      for (int r = 0; r < 4; ++r) acc[i][j][r] = 0.0f;

  for (int kt = 0; kt < K; kt += 32) {
    const bf16x8 va0 = *(const bf16x8*)(gA0 + kt);
    const bf16x8 va1 = *(const bf16x8*)(gA1 + kt);
    const bf16x8 vb0 = *(const bf16x8*)(gB0 + kt);
    const bf16x8 vb1 = *(const bf16x8*)(gB1 + kt);
    __syncthreads();
    *(bf16x8*)(As + c0 * 8) = va0;
    *(bf16x8*)(As + c1 * 8) = va1;
    *(bf16x8*)(Bs + c0 * 8) = vb0;
    *(bf16x8*)(Bs + c1 * 8) = vb1;
    __syncthreads();

    bf16x8 af[4], bfr[4];
#pragma unroll
    for (int i = 0; i < 4; ++i)
      af[i] = *(const bf16x8*)(As + (wr + i * 16 + lrow) * 32 + quad * 8);
#pragma unroll
    for (int j = 0; j < 4; ++j)
      bfr[j] = *(const bf16x8*)(Bs + (wc + j * 16 + lrow) * 32 + quad * 8);

#pragma unroll
    for (int i = 0; i < 4; ++i)
#pragma unroll
      for (int j = 0; j < 4; ++j)
        acc[i][j] = __builtin_amdgcn_mfma_f32_16x16x32_bf16(af[i], bfr[j],
                                                            acc[i][j], 0, 0, 0);
  }

  // epilogue: C/D layout col=lane&15, row=quad*4+reg
  if (EPI == 1) {
    float* C = (float*)Cp;
#pragma unroll
    for (int i = 0; i < 4; ++i)
#pragma unroll
      for (int j = 0; j < 4; ++j)
#pragma unroll
        for (int r = 0; r < 4; ++r) {
          const int row = m0 + wr + i * 16 + quad * 4 + r;
          const int col = n0 + wc + j * 16 + lrow;
          C[(size_t)row * ldc + col] = acc[i][j][r] * scale;
        }
  } else if (EPI == 2) {
    u16* C = (u16*)Cp;
#pragma unroll
    for (int i = 0; i < 4; ++i)
#pragma unroll
      for (int j = 0; j < 4; ++j)
#pragma unroll
        for (int r = 0; r < 4; ++r) {
          const int row = m0 + wr + i * 16 + quad * 4 + r;
          const int col = n0 + wc + j * 16 + lrow;
          C[(size_t)row * ldc + col] = f2bf(acc[i][j][r]);
        }
  } else {
    float bv[4];
#pragma unroll
    for (int j = 0; j < 4; ++j) bv[j] = biasf[n0 + wc + j * 16 + lrow];
    const bool f32out = (of32 != nullptr) && (*of32 != 0);
    if (f32out) {
      float* C = (float*)Cp;
#pragma unroll
      for (int i = 0; i < 4; ++i)
#pragma unroll
        for (int j = 0; j < 4; ++j)
#pragma unroll
          for (int r = 0; r < 4; ++r) {
            const int row = m0 + wr + i * 16 + quad * 4 + r;
            const int col = n0 + wc + j * 16 + lrow;
            C[(size_t)row * ldc + col] = acc[i][j][r] + bv[j];
          }
    } else {
      u16* C = (u16*)Cp;
#pragma unroll
      for (int i = 0; i < 4; ++i)
#pragma unroll
        for (int j = 0; j < 4; ++j)
#pragma unroll
          for (int r = 0; r < 4; ++r) {
            const int row = m0 + wr + i * 16 + quad * 4 + r;
            const int col = n0 + wc + j * 16 + lrow;
            C[(size_t)row * ldc + col] = f2bf(acc[i][j][r] + bv[j]);
          }
    }
  }
}

// ---- GEMM kernels --------------------------------------------------------

__global__ __launch_bounds__(256) void k_gemm_bias(
    const u16* __restrict__ A, const u16* __restrict__ BT,
    void* __restrict__ C, const float* __restrict__ biasf,
    const int* __restrict__ of32)
{
  gemm_core<0>(A, EMB, BT, EMB, C, EMB, biasf, of32, 1.0f, EMB,
               blockIdx.y * 128, blockIdx.x * 128);
}

__global__ __launch_bounds__(256) void k_gemm_scores(
    const u16* __restrict__ Q, const u16* __restrict__ Kmat,
    float* __restrict__ S, int b0)
{
  const int b = b0 + blockIdx.z;
  gemm_core<1>(Q    + (size_t)b * SEQ * EMB, EMB,
               Kmat + (size_t)b * SEQ * EMB, EMB,
               S + (size_t)blockIdx.z * SEQ * SEQ, SEQ,
               nullptr, nullptr, 0.03608439182435161f /* 1/sqrt(768) */, EMB,
               blockIdx.y * 128, blockIdx.x * 128);
}

__global__ __launch_bounds__(256) void k_gemm_pv(
    const u16* __restrict__ P, const u16* __restrict__ VT,
    u16* __restrict__ O, int b0)
{
  const int b = b0 + blockIdx.z;
  gemm_core<2>(P  + (size_t)blockIdx.z * SEQ * 4096, 4096,
               VT + (size_t)b * EMB * SEQ, SEQ,
               O  + (size_t)b * SEQ * EMB, EMB,
               nullptr, nullptr, 1.0f, SEQ,
               blockIdx.y * 128, blockIdx.x * 128);
}

// row softmax over fp32 S row, write bf16 P in place (row pitch 4096 u16)
__global__ __launch_bounds__(256) void k_softmax(float* __restrict__ S)
{
  float* row = S + ((size_t)blockIdx.y * SEQ + blockIdx.x) * SEQ;
  u16* prow = (u16*)row;
  const int tid = threadIdx.x;

  float v[8];
#pragma unroll
  for (int i = 0; i < 8; ++i) v[i] = row[tid + i * 256];

  float mx = v[0];
#pragma unroll
  for (int i = 1; i < 8; ++i) mx = fmaxf(mx, v[i]);
#pragma unroll
  for (int off = 32; off > 0; off >>= 1) mx = fmaxf(mx, __shfl_down(mx, off));
  __shared__ float red[4], red2[4];
  if ((tid & 63) == 0) red[tid >> 6] = mx;
  __syncthreads();
  mx = fmaxf(fmaxf(red[0], red[1]), fmaxf(red[2], red[3]));

  float s = 0.0f;
#pragma unroll
  for (int i = 0; i < 8; ++i) { v[i] = __expf(v[i] - mx); s += v[i]; }
#pragma unroll
  for (int off = 32; off > 0; off >>= 1) s += __shfl_down(s, off);
  if ((tid & 63) == 0) red2[tid >> 6] = s;
  __syncthreads();
  s = red2[0] + red2[1] + red2[2] + red2[3];
  const float inv = 1.0f / s;
#pragma unroll
  for (int i = 0; i < 8; ++i) prow[tid + i * 256] = f2bf(v[i] * inv);
}

// V (in d_out scratch) -> VT
__global__ __launch_bounds__(256) void k_transpose_v(
    const u16* __restrict__ V, u16* __restrict__ VT)
{
  __shared__ u16 t[32][33];
  const int b = blockIdx.z;
  const u16* in = V + (size_t)b * SEQ * EMB;
  u16* out = VT + (size_t)b * EMB * SEQ;
  const int c0 = blockIdx.x * 32, r0 = blockIdx.y * 32;
  const int tx = threadIdx.x, ty = threadIdx.y;
#pragma unroll
  for (int i = 0; i < 4; ++i)
    t[ty + i * 8][tx] = in[(size_t)(r0 + ty + i * 8) * EMB + c0 + tx];
  __syncthreads();
#pragma unroll
  for (int i = 0; i < 4; ++i)
    out[(size_t)(c0 + ty + i * 8) * SEQ + r0 + tx] = t[tx][ty + i * 8];
}

// ---- host launch ---------------------------------------------------------

extern "C" void kernel_launch(void* const* d_in, const int* in_sizes, int n_in,
                              void* d_out, int out_size, void* d_ws, size_t ws_size,
                              hipStream_t stream)
{
  (void)in_sizes; (void)n_in; (void)out_size;
  const void* x  = d_in[0];
  const void* Wq = d_in[1];
  const void* bq = d_in[2];
  const void* Wk = d_in[3];
  const void* bk = d_in[4];
  const void* Wv = d_in[5];
  const void* bv = d_in[6];
  const void* Wo = d_in[7];
  const void* bo = d_in[8];

  char* ws = (char*)d_ws;
  size_t off = 0;
  auto alloc = [&](size_t bytes) -> void* {
    void* p = ws + off;
    off += (bytes + 255) & ~(size_t)255;
    return p;
  };
  const size_t SZ_QKV = (size_t)NB * SEQ * EMB * 2;      // 25,165,824 B
  int*   flag  = (int*)alloc(256);
  u16*   xb    = (u16*)alloc(SZ_QKV);
  u16*   Q     = (u16*)alloc(SZ_QKV);    // reused as O
  u16*   Kb    = (u16*)alloc(SZ_QKV);
  u16*   VT    = (u16*)alloc(SZ_QKV);
  u16*   WT    = (u16*)alloc((size_t)4 * EMB * EMB * 2);
  float* biasf = (float*)alloc((size_t)4 * EMB * 4);
  float* S     = (float*)(ws + off);
  size_t rem   = (ws_size > off) ? ws_size - off : 0;
  u16*   O     = Q;           // alias: Q[b] dead once scores[b] computed
  u16*   V     = (u16*)d_out; // d_out as scratch for V (dead after VT)

  int GB = 8;
  while (GB > 1 && (size_t)GB * ((size_t)SEQ * SEQ * 4) > rem) GB >>= 1;

  // 0. dtype detect + normalize inputs to bf16
  k_detect<<<1, 256, 0, stream>>>((const u16*)x, flag);
  const int n4 = NB * SEQ * EMB / 4;
  k_convert_x<<<(n4 + 255) / 256, 256, 0, stream>>>(x, xb, flag, n4);
  k_transpose_w<<<dim3(EMB / 32, EMB / 32, 4), dim3(32, 8), 0, stream>>>(
      Wq, Wk, Wv, Wo, WT, flag);
  k_convert_bias<<<4, 256, 0, stream>>>(bq, bk, bv, bo, biasf, flag);

  // 1. Q/K/V projections (M=16384, N=768, K=768)
  k_gemm_bias<<<dim3(6, 128), 256, 0, stream>>>(xb, WT,               Q, biasf,           nullptr);
  k_gemm_bias<<<dim3(6, 128), 256, 0, stream>>>(xb, WT + 1 * EMB*EMB, Kb, biasf + EMB,     nullptr);
  k_gemm_bias<<<dim3(6, 128), 256, 0, stream>>>(xb, WT + 2 * EMB*EMB, V, biasf + 2 * EMB, nullptr);

  // 2. V -> V^T per batch
  k_transpose_v<<<dim3(EMB / 32, SEQ / 32, NB), dim3(32, 8), 0, stream>>>(V, VT);

  // 3. attention per batch-group
  for (int g = 0; g < NB; g += GB) {
    k_gemm_scores<<<dim3(16, 16, GB), 256, 0, stream>>>(Q, Kb, S, g);
    k_softmax<<<dim3(SEQ, GB), 256, 0, stream>>>(S);
    k_gemm_pv<<<dim3(6, 16, GB), 256, 0, stream>>>((const u16*)S, VT, O, g);
  }

  // 4. output projection (dtype of d_out per flag)
  k_gemm_bias<<<dim3(6, 128), 256, 0, stream>>>(O, WT + 3 * EMB*EMB, d_out,
                                                biasf + 3 * EMB, flag);
}

// Round 4
// 476.865 us; speedup vs baseline: 1.0446x; 1.0446x over previous
//
#include <hip/hip_runtime.h>
#include <stdint.h>

typedef unsigned short u16;
typedef __attribute__((ext_vector_type(8))) __bf16 bf16x8;
typedef __attribute__((ext_vector_type(4))) float f32x4;

#define SEQ 2048
#define EMB 768
#define NB  8
#define LDQKV (3 * EMB)   // 2304, row pitch of fused QKV buffer

__device__ __forceinline__ u16 f2bf(float f) {
  union { float f; uint32_t u; } a; a.f = f;
  uint32_t r = a.u + 0x7fffu + ((a.u >> 16) & 1u);
  return (u16)(r >> 16);
}
__device__ __forceinline__ float bf2f(u16 h) {
  union { uint32_t u; float f; } a; a.u = ((uint32_t)h) << 16;
  return a.f;
}

// ---------------------------------------------------------------------------
// dtype detector (1 = fp32 inputs). Works for both layouts: fp32 low-halves
// give uniform bit patterns (~37% hit [160,254]); bf16 N(0,1) gives ~0%.
// ---------------------------------------------------------------------------
__global__ __launch_bounds__(256) void k_detect(const u16* __restrict__ x,
                                                int* __restrict__ flag)
{
  const int tid = threadIdx.x;
  int bad = 0;
#pragma unroll
  for (int i = 0; i < 4; ++i) {
    const u16 h = x[(tid * 4 + i) * 2];
    const int e = (h >> 7) & 0xFF;
    bad += (e >= 160 && e <= 254) ? 1 : 0;
  }
#pragma unroll
  for (int off = 32; off > 0; off >>= 1) bad += __shfl_down(bad, off);
  __shared__ int cnt[4];
  if ((tid & 63) == 0) cnt[tid >> 6] = bad;
  __syncthreads();
  if (tid == 0) *flag = (cnt[0] + cnt[1] + cnt[2] + cnt[3] > 200) ? 1 : 0;
}

__global__ __launch_bounds__(256) void k_convert_x(
    const void* __restrict__ src, u16* __restrict__ dst,
    const int* __restrict__ flag, int n4)
{
  const int i = blockIdx.x * 256 + threadIdx.x;
  if (i >= n4) return;
  if (*flag) {
    const float4 f = ((const float4*)src)[i];
    ushort4 o;
    o.x = f2bf(f.x); o.y = f2bf(f.y); o.z = f2bf(f.z); o.w = f2bf(f.w);
    ((ushort4*)dst)[i] = o;
  } else {
    ((ushort4*)dst)[i] = ((const ushort4*)src)[i];
  }
}

// biases -> fp32 [4*768]: q@0, k@768, v@1536 (QKV-fused order), o@2304
__global__ __launch_bounds__(256) void k_convert_bias(
    const void* __restrict__ b0, const void* __restrict__ b1,
    const void* __restrict__ b2, const void* __restrict__ b3,
    float* __restrict__ dst, const int* __restrict__ flag)
{
  const int z = blockIdx.x;
  const void* src = (z == 0) ? b0 : (z == 1) ? b1 : (z == 2) ? b2 : b3;
  const int f32 = *flag;
#pragma unroll
  for (int i = 0; i < 3; ++i) {
    const int j = threadIdx.x + i * 256;
    const float v = f32 ? ((const float*)src)[j] : bf2f(((const u16*)src)[j]);
    dst[z * EMB + j] = v;
  }
}

// weights: convert + transpose -> WT (bf16). Rows 0..2303 = Wq^T|Wk^T|Wv^T
// (the fused-GEMM B^T), rows 2304..3071 = Wo^T.
__global__ __launch_bounds__(256) void k_transpose_w(
    const void* __restrict__ W0, const void* __restrict__ W1,
    const void* __restrict__ W2, const void* __restrict__ W3,
    u16* __restrict__ WT, const int* __restrict__ flag)
{
  __shared__ u16 t[32][33];
  const int z = blockIdx.z;
  const void* in = (z == 0) ? W0 : (z == 1) ? W1 : (z == 2) ? W2 : W3;
  u16* out = WT + (size_t)z * EMB * EMB;
  const int c0 = blockIdx.x * 32, r0 = blockIdx.y * 32;
  const int tx = threadIdx.x, ty = threadIdx.y;
  const int f32 = *flag;
#pragma unroll
  for (int i = 0; i < 4; ++i) {
    const size_t idx = (size_t)(r0 + ty + i * 8) * EMB + c0 + tx;
    t[ty + i * 8][tx] = f32 ? f2bf(((const float*)in)[idx])
                            : ((const u16*)in)[idx];
  }
  __syncthreads();
#pragma unroll
  for (int i = 0; i < 4; ++i)
    out[(size_t)(c0 + ty + i * 8) * EMB + r0 + tx] = t[tx][ty + i * 8];
}

// ---------------------------------------------------------------------------
// 128x128 MFMA GEMM tile: C[m,n] = sum_k A[m,k] * BT[n,k]
// 256 threads = 4 waves, each 64x64 (4x4 MFMA 16x16x32 tiles). BK=32.
// Staging: async global_load_lds width=16 (m97 structure).
// EPI: 0 = bias add (bf16 or fp32 out per of32); 1 = f32 out * scale;
//      2 = bf16 out.
// ---------------------------------------------------------------------------
template <int EPI>
__device__ __forceinline__ void gemm_core(
    const u16* __restrict__ A, int lda,
    const u16* __restrict__ BT, int ldbt,
    void* __restrict__ Cp, int ldc,
    const float* __restrict__ biasf, const int* __restrict__ of32,
    float scale, int K, int m0, int n0)
{
  __shared__ __align__(16) u16 As[128 * 32];
  __shared__ __align__(16) u16 Bs[128 * 32];
  const int tid  = threadIdx.x;
  const int lane = tid & 63;
  const int wave = tid >> 6;
  const int wr   = (wave >> 1) * 64;
  const int wc   = (wave & 1) * 64;
  const int lrow = lane & 15;
  const int quad = lane >> 4;

  f32x4 acc[4][4];
#pragma unroll
  for (int i = 0; i < 4; ++i)
#pragma unroll
    for (int j = 0; j < 4; ++j)
#pragma unroll
      for (int r = 0; r < 4; ++r) acc[i][j][r] = 0.0f;

  for (int kt = 0; kt < K; kt += 32) {
    // 512 16B chunks per buffer; chunk c -> row c>>2, k-seg c&3.
    // LDS dst is wave-uniform base; HW scatters lane l at base + l*16B.
#pragma unroll
    for (int i = 0; i < 2; ++i) {
      const int c = wave * 128 + i * 64 + lane;
      const int r = c >> 2, s = c & 3;
      const u16* ga = A  + (size_t)(m0 + r) * lda  + kt + s * 8;
      const u16* gb = BT + (size_t)(n0 + r) * ldbt + kt + s * 8;
      u16* la = As + (size_t)(wave * 128 + i * 64) * 8;
      u16* lb = Bs + (size_t)(wave * 128 + i * 64) * 8;
      __builtin_amdgcn_global_load_lds(
          (const __attribute__((address_space(1))) void*)ga,
          (__attribute__((address_space(3))) void*)la, 16, 0, 0);
      __builtin_amdgcn_global_load_lds(
          (const __attribute__((address_space(1))) void*)gb,
          (__attribute__((address_space(3))) void*)lb, 16, 0, 0);
    }
    __syncthreads();  // drains vmcnt: LDS tiles filled

    bf16x8 af[4], bfr[4];
#pragma unroll
    for (int i = 0; i < 4; ++i)
      af[i] = *(const bf16x8*)(As + (wr + i * 16 + lrow) * 32 + quad * 8);
#pragma unroll
    for (int j = 0; j < 4; ++j)
      bfr[j] = *(const bf16x8*)(Bs + (wc + j * 16 + lrow) * 32 + quad * 8);

#pragma unroll
    for (int i = 0; i < 4; ++i)
#pragma unroll
      for (int j = 0; j < 4; ++j)
        acc[i][j] = __builtin_amdgcn_mfma_f32_16x16x32_bf16(af[i], bfr[j],
                                                            acc[i][j], 0, 0, 0);
    __syncthreads();  // ds_reads done before next iter overwrites LDS
  }

  // epilogue: C/D layout col=lane&15, row=quad*4+reg
  if (EPI == 1) {
    float* C = (float*)Cp;
#pragma unroll
    for (int i = 0; i < 4; ++i)
#pragma unroll
      for (int j = 0; j < 4; ++j)
#pragma unroll
        for (int r = 0; r < 4; ++r) {
          const int row = m0 + wr + i * 16 + quad * 4 + r;
          const int col = n0 + wc + j * 16 + lrow;
          C[(size_t)row * ldc + col] = acc[i][j][r] * scale;
        }
  } else if (EPI == 2) {
    u16* C = (u16*)Cp;
#pragma unroll
    for (int i = 0; i < 4; ++i)
#pragma unroll
      for (int j = 0; j < 4; ++j)
#pragma unroll
        for (int r = 0; r < 4; ++r) {
          const int row = m0 + wr + i * 16 + quad * 4 + r;
          const int col = n0 + wc + j * 16 + lrow;
          C[(size_t)row * ldc + col] = f2bf(acc[i][j][r]);
        }
  } else {
    float bv[4];
#pragma unroll
    for (int j = 0; j < 4; ++j) bv[j] = biasf[n0 + wc + j * 16 + lrow];
    const bool f32out = (of32 != nullptr) && (*of32 != 0);
    if (f32out) {
      float* C = (float*)Cp;
#pragma unroll
      for (int i = 0; i < 4; ++i)
#pragma unroll
        for (int j = 0; j < 4; ++j)
#pragma unroll
          for (int r = 0; r < 4; ++r) {
            const int row = m0 + wr + i * 16 + quad * 4 + r;
            const int col = n0 + wc + j * 16 + lrow;
            C[(size_t)row * ldc + col] = acc[i][j][r] + bv[j];
          }
    } else {
      u16* C = (u16*)Cp;
#pragma unroll
      for (int i = 0; i < 4; ++i)
#pragma unroll
        for (int j = 0; j < 4; ++j)
#pragma unroll
          for (int r = 0; r < 4; ++r) {
            const int row = m0 + wr + i * 16 + quad * 4 + r;
            const int col = n0 + wc + j * 16 + lrow;
            C[(size_t)row * ldc + col] = f2bf(acc[i][j][r] + bv[j]);
          }
    }
  }
}

// ---- GEMM kernels --------------------------------------------------------

// fused QKV projection: C[16384][2304] = xb @ [Wq|Wk|Wv] + [bq|bk|bv]
__global__ __launch_bounds__(256) void k_gemm_qkv(
    const u16* __restrict__ A, const u16* __restrict__ BT,
    u16* __restrict__ C, const float* __restrict__ biasf)
{
  gemm_core<0>(A, EMB, BT, EMB, C, LDQKV, biasf, nullptr, 1.0f, EMB,
               blockIdx.y * 128, blockIdx.x * 128);
}

// output projection: d_out = O @ Wo + bo (dtype per flag)
__global__ __launch_bounds__(256) void k_gemm_out(
    const u16* __restrict__ A, const u16* __restrict__ BT,
    void* __restrict__ C, const float* __restrict__ biasf,
    const int* __restrict__ of32)
{
  gemm_core<0>(A, EMB, BT, EMB, C, EMB, biasf, of32, 1.0f, EMB,
               blockIdx.y * 128, blockIdx.x * 128);
}

// S[z] = Q[b] @ K[b]^T * scale   (fp32 out), Q/K strided in QKV buffer
__global__ __launch_bounds__(256) void k_gemm_scores(
    const u16* __restrict__ QKV, float* __restrict__ S, int b0)
{
  const int b = b0 + blockIdx.z;
  const u16* base = QKV + (size_t)b * SEQ * LDQKV;
  gemm_core<1>(base, LDQKV,              // Q
               base + EMB, LDQKV,        // K
               S + (size_t)blockIdx.z * SEQ * SEQ, SEQ,
               nullptr, nullptr, 0.03608439182435161f /* 1/sqrt(768) */, EMB,
               blockIdx.y * 128, blockIdx.x * 128);
}

// O[b] = P[b] @ V[b]  with P bf16 (row pitch 4096 u16) and VT[b] = V[b]^T
__global__ __launch_bounds__(256) void k_gemm_pv(
    const u16* __restrict__ P, const u16* __restrict__ VT,
    u16* __restrict__ O, int b0)
{
  const int b = b0 + blockIdx.z;
  gemm_core<2>(P  + (size_t)blockIdx.z * SEQ * 4096, 4096,
               VT + (size_t)b * EMB * SEQ, SEQ,
               O  + (size_t)b * SEQ * EMB, EMB,
               nullptr, nullptr, 1.0f, SEQ,
               blockIdx.y * 128, blockIdx.x * 128);
}

// row softmax over fp32 S row, write bf16 P in place (row pitch 4096 u16)
__global__ __launch_bounds__(256) void k_softmax(float* __restrict__ S)
{
  float* row = S + ((size_t)blockIdx.y * SEQ + blockIdx.x) * SEQ;
  u16* prow = (u16*)row;
  const int tid = threadIdx.x;

  float v[8];
#pragma unroll
  for (int i = 0; i < 8; ++i) v[i] = row[tid + i * 256];

  float mx = v[0];
#pragma unroll
  for (int i = 1; i < 8; ++i) mx = fmaxf(mx, v[i]);
#pragma unroll
  for (int off = 32; off > 0; off >>= 1) mx = fmaxf(mx, __shfl_down(mx, off));
  __shared__ float red[4], red2[4];
  if ((tid & 63) == 0) red[tid >> 6] = mx;
  __syncthreads();
  mx = fmaxf(fmaxf(red[0], red[1]), fmaxf(red[2], red[3]));

  float s = 0.0f;
#pragma unroll
  for (int i = 0; i < 8; ++i) { v[i] = __expf(v[i] - mx); s += v[i]; }
#pragma unroll
  for (int off = 32; off > 0; off >>= 1) s += __shfl_down(s, off);
  if ((tid & 63) == 0) red2[tid >> 6] = s;
  __syncthreads();
  s = red2[0] + red2[1] + red2[2] + red2[3];
  const float inv = 1.0f / s;
#pragma unroll
  for (int i = 0; i < 8; ++i) prow[tid + i * 256] = f2bf(v[i] * inv);
}

// V (strided in QKV at col offset 1536) -> VT [768][2048] per batch
__global__ __launch_bounds__(256) void k_transpose_v(
    const u16* __restrict__ QKV, u16* __restrict__ VT)
{
  __shared__ u16 t[32][33];
  const int b = blockIdx.z;
  const u16* in = QKV + (size_t)b * SEQ * LDQKV + 2 * EMB;
  u16* out = VT + (size_t)b * EMB * SEQ;
  const int c0 = blockIdx.x * 32, r0 = blockIdx.y * 32;
  const int tx = threadIdx.x, ty = threadIdx.y;
#pragma unroll
  for (int i = 0; i < 4; ++i)
    t[ty + i * 8][tx] = in[(size_t)(r0 + ty + i * 8) * LDQKV + c0 + tx];
  __syncthreads();
#pragma unroll
  for (int i = 0; i < 4; ++i)
    out[(size_t)(c0 + ty + i * 8) * SEQ + r0 + tx] = t[tx][ty + i * 8];
}

// ---- host launch ---------------------------------------------------------

extern "C" void kernel_launch(void* const* d_in, const int* in_sizes, int n_in,
                              void* d_out, int out_size, void* d_ws, size_t ws_size,
                              hipStream_t stream)
{
  (void)in_sizes; (void)n_in; (void)out_size;
  const void* x  = d_in[0];
  const void* Wq = d_in[1];
  const void* bq = d_in[2];
  const void* Wk = d_in[3];
  const void* bk = d_in[4];
  const void* Wv = d_in[5];
  const void* bv = d_in[6];
  const void* Wo = d_in[7];
  const void* bo = d_in[8];

  char* ws = (char*)d_ws;
  size_t off = 0;
  auto alloc = [&](size_t bytes) -> void* {
    void* p = ws + off;
    off += (bytes + 255) & ~(size_t)255;
    return p;
  };
  int*   flag  = (int*)alloc(256);
  u16*   xb    = (u16*)alloc((size_t)NB * SEQ * EMB * 2);       // 25.2 MB
  u16*   QKV   = (u16*)alloc((size_t)NB * SEQ * LDQKV * 2);     // 75.5 MB
  u16*   VT    = (u16*)alloc((size_t)NB * EMB * SEQ * 2);       // 25.2 MB
  u16*   O     = (u16*)alloc((size_t)NB * SEQ * EMB * 2);       // 25.2 MB
  u16*   WT    = (u16*)alloc((size_t)4 * EMB * EMB * 2);        //  4.7 MB
  float* biasf = (float*)alloc((size_t)4 * EMB * 4);
  float* S     = (float*)(ws + off);
  size_t rem   = (ws_size > off) ? ws_size - off : 0;

  int GB = 8;  // batches per S-group; shrink if workspace is tight
  while (GB > 1 && (size_t)GB * ((size_t)SEQ * SEQ * 4) > rem) GB >>= 1;

  // 0. dtype detect + normalize inputs to bf16
  k_detect<<<1, 256, 0, stream>>>((const u16*)x, flag);
  const int n4 = NB * SEQ * EMB / 4;
  k_convert_x<<<(n4 + 255) / 256, 256, 0, stream>>>(x, xb, flag, n4);
  k_transpose_w<<<dim3(EMB / 32, EMB / 32, 4), dim3(32, 8), 0, stream>>>(
      Wq, Wk, Wv, Wo, WT, flag);
  k_convert_bias<<<4, 256, 0, stream>>>(bq, bk, bv, bo, biasf, flag);

  // 1. fused QKV projection (M=16384, N=2304, K=768)
  k_gemm_qkv<<<dim3(18, 128), 256, 0, stream>>>(xb, WT, QKV, biasf);

  // 2. V -> V^T per batch
  k_transpose_v<<<dim3(EMB / 32, SEQ / 32, NB), dim3(32, 8), 0, stream>>>(QKV, VT);

  // 3. attention per batch-group
  for (int g = 0; g < NB; g += GB) {
    k_gemm_scores<<<dim3(16, 16, GB), 256, 0, stream>>>(QKV, S, g);
    k_softmax<<<dim3(SEQ, GB), 256, 0, stream>>>(S);
    k_gemm_pv<<<dim3(6, 16, GB), 256, 0, stream>>>((const u16*)S, VT, O, g);
  }

  // 4. output projection (dtype of d_out per flag)
  k_gemm_out<<<dim3(6, 128), 256, 0, stream>>>(O, WT + 3 * EMB * EMB, d_out,
                                               biasf + 3 * EMB, flag);
}

// Round 5
// 441.458 us; speedup vs baseline: 1.1283x; 1.0802x over previous
//
#include <hip/hip_runtime.h>
#include <hip/hip_fp16.h>
#include <stdint.h>

typedef unsigned short u16;
typedef __attribute__((ext_vector_type(8))) __bf16 bf16x8;
typedef __attribute__((ext_vector_type(4))) float f32x4;

#define SEQ 2048
#define EMB 768
#define NB  8
#define LDQK (2 * EMB)    // 1536: row pitch of fused Q|K buffer
#define NQKV (3 * EMB)    // 2304: N of fused QKV GEMM

__device__ __forceinline__ u16 f2bf(float f) {
  union { float f; uint32_t u; } a; a.f = f;
  uint32_t r = a.u + 0x7fffu + ((a.u >> 16) & 1u);
  return (u16)(r >> 16);
}
__device__ __forceinline__ float bf2f(u16 h) {
  union { uint32_t u; float f; } a; a.u = ((uint32_t)h) << 16;
  return a.f;
}

// ---------------------------------------------------------------------------
// dtype detect (1 = fp32 inputs) + bias conversion fused.
// fp32 low-half u16s have ~37% exponent fields in [160,254]; bf16 N(0,1) ~0%.
// ---------------------------------------------------------------------------
__global__ __launch_bounds__(256) void k_detect_bias(
    const u16* __restrict__ x, int* __restrict__ flag,
    const void* __restrict__ b0, const void* __restrict__ b1,
    const void* __restrict__ b2, const void* __restrict__ b3,
    float* __restrict__ biasf)
{
  const int tid = threadIdx.x;
  int bad = 0;
#pragma unroll
  for (int i = 0; i < 4; ++i) {
    const u16 h = x[(tid * 4 + i) * 2];
    const int e = (h >> 7) & 0xFF;
    bad += (e >= 160 && e <= 254) ? 1 : 0;
  }
#pragma unroll
  for (int off = 32; off > 0; off >>= 1) bad += __shfl_down(bad, off);
  __shared__ int cnt[4];
  __shared__ int sflag;
  if ((tid & 63) == 0) cnt[tid >> 6] = bad;
  __syncthreads();
  if (tid == 0) {
    const int f = (cnt[0] + cnt[1] + cnt[2] + cnt[3] > 200) ? 1 : 0;
    sflag = f;
    *flag = f;
  }
  __syncthreads();
  const int f32 = sflag;
#pragma unroll
  for (int z = 0; z < 4; ++z) {
    const void* src = (z == 0) ? b0 : (z == 1) ? b1 : (z == 2) ? b2 : b3;
#pragma unroll
    for (int i = 0; i < 3; ++i) {
      const int j = tid + i * 256;
      biasf[z * EMB + j] = f32 ? ((const float*)src)[j]
                               : bf2f(((const u16*)src)[j]);
    }
  }
}

__global__ __launch_bounds__(256) void k_convert_x(
    const void* __restrict__ src, u16* __restrict__ dst,
    const int* __restrict__ flag, int n4)
{
  const int i = blockIdx.x * 256 + threadIdx.x;
  if (i >= n4) return;
  if (*flag) {
    const float4 f = ((const float4*)src)[i];
    ushort4 o;
    o.x = f2bf(f.x); o.y = f2bf(f.y); o.z = f2bf(f.z); o.w = f2bf(f.w);
    ((ushort4*)dst)[i] = o;
  } else {
    ((ushort4*)dst)[i] = ((const ushort4*)src)[i];
  }
}

// weights: convert + transpose -> WT (bf16). Rows 0..2303 = Wq^T|Wk^T|Wv^T,
// rows 2304..3071 = Wo^T.
__global__ __launch_bounds__(256) void k_transpose_w(
    const void* __restrict__ W0, const void* __restrict__ W1,
    const void* __restrict__ W2, const void* __restrict__ W3,
    u16* __restrict__ WT, const int* __restrict__ flag)
{
  __shared__ u16 t[32][33];
  const int z = blockIdx.z;
  const void* in = (z == 0) ? W0 : (z == 1) ? W1 : (z == 2) ? W2 : W3;
  u16* out = WT + (size_t)z * EMB * EMB;
  const int c0 = blockIdx.x * 32, r0 = blockIdx.y * 32;
  const int tx = threadIdx.x, ty = threadIdx.y;
  const int f32 = *flag;
#pragma unroll
  for (int i = 0; i < 4; ++i) {
    const size_t idx = (size_t)(r0 + ty + i * 8) * EMB + c0 + tx;
    t[ty + i * 8][tx] = f32 ? f2bf(((const float*)in)[idx])
                            : ((const u16*)in)[idx];
  }
  __syncthreads();
#pragma unroll
  for (int i = 0; i < 4; ++i)
    out[(size_t)(c0 + ty + i * 8) * EMB + r0 + tx] = t[tx][ty + i * 8];
}

// ---------------------------------------------------------------------------
// 128x128 MFMA GEMM tile: C[m,n] = sum_k A[m,k] * BT[n,k]
// 256 threads = 4 waves, each 64x64 (4x4 MFMA 16x16x32 tiles). BK=32.
// Staging: async global_load_lds width=16 (m97 structure).
// EPI: 0 = bias add (bf16/fp32 out per of32); 2 = bf16 out;
//      3 = f16 out * scale; 4 = QKV fused (Q/K row-major + V transposed)
// ---------------------------------------------------------------------------
template <int EPI>
__device__ __forceinline__ void gemm_core(
    const u16* __restrict__ A, int lda,
    const u16* __restrict__ BT, int ldbt,
    void* __restrict__ Cp, int ldc,
    void* __restrict__ Cp2,               // EPI=4: VT base (batch-resolved)
    const float* __restrict__ biasf, const int* __restrict__ of32,
    float scale, int K, int m0, int n0)
{
  __shared__ __align__(16) u16 As[128 * 32];
  __shared__ __align__(16) u16 Bs[128 * 32];
  const int tid  = threadIdx.x;
  const int lane = tid & 63;
  const int wave = tid >> 6;
  const int wr   = (wave >> 1) * 64;
  const int wc   = (wave & 1) * 64;
  const int lrow = lane & 15;
  const int quad = lane >> 4;

  f32x4 acc[4][4];
#pragma unroll
  for (int i = 0; i < 4; ++i)
#pragma unroll
    for (int j = 0; j < 4; ++j)
#pragma unroll
      for (int r = 0; r < 4; ++r) acc[i][j][r] = 0.0f;

  for (int kt = 0; kt < K; kt += 32) {
    // 512 16B chunks per buffer; chunk c -> row c>>2, k-seg c&3.
    // LDS dst is wave-uniform base; HW scatters lane l at base + l*16B.
#pragma unroll
    for (int i = 0; i < 2; ++i) {
      const int c = wave * 128 + i * 64 + lane;
      const int r = c >> 2, s = c & 3;
      const u16* ga = A  + (size_t)(m0 + r) * lda  + kt + s * 8;
      const u16* gb = BT + (size_t)(n0 + r) * ldbt + kt + s * 8;
      u16* la = As + (size_t)(wave * 128 + i * 64) * 8;
      u16* lb = Bs + (size_t)(wave * 128 + i * 64) * 8;
      __builtin_amdgcn_global_load_lds(
          (const __attribute__((address_space(1))) void*)ga,
          (__attribute__((address_space(3))) void*)la, 16, 0, 0);
      __builtin_amdgcn_global_load_lds(
          (const __attribute__((address_space(1))) void*)gb,
          (__attribute__((address_space(3))) void*)lb, 16, 0, 0);
    }
    __syncthreads();  // drains vmcnt: LDS tiles filled

    bf16x8 af[4], bfr[4];
#pragma unroll
    for (int i = 0; i < 4; ++i)
      af[i] = *(const bf16x8*)(As + (wr + i * 16 + lrow) * 32 + quad * 8);
#pragma unroll
    for (int j = 0; j < 4; ++j)
      bfr[j] = *(const bf16x8*)(Bs + (wc + j * 16 + lrow) * 32 + quad * 8);

#pragma unroll
    for (int i = 0; i < 4; ++i)
#pragma unroll
      for (int j = 0; j < 4; ++j)
        acc[i][j] = __builtin_amdgcn_mfma_f32_16x16x32_bf16(af[i], bfr[j],
                                                            acc[i][j], 0, 0, 0);
    __syncthreads();  // ds_reads done before next iter overwrites LDS
  }

  // epilogue: C/D layout col=lane&15, row=quad*4+reg
  if (EPI == 3) {
    u16* C = (u16*)Cp;
#pragma unroll
    for (int i = 0; i < 4; ++i)
#pragma unroll
      for (int j = 0; j < 4; ++j)
#pragma unroll
        for (int r = 0; r < 4; ++r) {
          const int row = m0 + wr + i * 16 + quad * 4 + r;
          const int col = n0 + wc + j * 16 + lrow;
          C[(size_t)row * ldc + col] =
              __half_as_ushort(__float2half(acc[i][j][r] * scale));
        }
  } else if (EPI == 2) {
    u16* C = (u16*)Cp;
#pragma unroll
    for (int i = 0; i < 4; ++i)
#pragma unroll
      for (int j = 0; j < 4; ++j)
#pragma unroll
        for (int r = 0; r < 4; ++r) {
          const int row = m0 + wr + i * 16 + quad * 4 + r;
          const int col = n0 + wc + j * 16 + lrow;
          C[(size_t)row * ldc + col] = f2bf(acc[i][j][r]);
        }
  } else if (EPI == 4) {
    float bv[4];
#pragma unroll
    for (int j = 0; j < 4; ++j) bv[j] = biasf[n0 + wc + j * 16 + lrow];
    if (n0 < LDQK) {
      // Q|K region: row-major into QK buffer (pitch ldc = 1536)
      u16* C = (u16*)Cp;
#pragma unroll
      for (int i = 0; i < 4; ++i)
#pragma unroll
        for (int j = 0; j < 4; ++j)
#pragma unroll
          for (int r = 0; r < 4; ++r) {
            const int row = m0 + wr + i * 16 + quad * 4 + r;
            const int col = n0 + wc + j * 16 + lrow;
            C[(size_t)row * ldc + col] = f2bf(acc[i][j][r] + bv[j]);
          }
    } else {
      // V region: transposed into VT[v][seq]; 4 consecutive seq per lane
      u16* VT = (u16*)Cp2;
      const int seqbase = (m0 & (SEQ - 1)) + wr;
#pragma unroll
      for (int i = 0; i < 4; ++i)
#pragma unroll
        for (int j = 0; j < 4; ++j) {
          const int v   = n0 - LDQK + wc + j * 16 + lrow;
          const int sq  = seqbase + i * 16 + quad * 4;
          ushort4 o;
          o.x = f2bf(acc[i][j][0] + bv[j]);
          o.y = f2bf(acc[i][j][1] + bv[j]);
          o.z = f2bf(acc[i][j][2] + bv[j]);
          o.w = f2bf(acc[i][j][3] + bv[j]);
          *(ushort4*)(VT + (size_t)v * SEQ + sq) = o;
        }
    }
  } else {  // EPI == 0
    float bv[4];
#pragma unroll
    for (int j = 0; j < 4; ++j) bv[j] = biasf[n0 + wc + j * 16 + lrow];
    const bool f32out = (of32 != nullptr) && (*of32 != 0);
    if (f32out) {
      float* C = (float*)Cp;
#pragma unroll
      for (int i = 0; i < 4; ++i)
#pragma unroll
        for (int j = 0; j < 4; ++j)
#pragma unroll
          for (int r = 0; r < 4; ++r) {
            const int row = m0 + wr + i * 16 + quad * 4 + r;
            const int col = n0 + wc + j * 16 + lrow;
            C[(size_t)row * ldc + col] = acc[i][j][r] + bv[j];
          }
    } else {
      u16* C = (u16*)Cp;
#pragma unroll
      for (int i = 0; i < 4; ++i)
#pragma unroll
        for (int j = 0; j < 4; ++j)
#pragma unroll
          for (int r = 0; r < 4; ++r) {
            const int row = m0 + wr + i * 16 + quad * 4 + r;
            const int col = n0 + wc + j * 16 + lrow;
            C[(size_t)row * ldc + col] = f2bf(acc[i][j][r] + bv[j]);
          }
    }
  }
}

// ---- GEMM kernels --------------------------------------------------------

// fused QKV projection: [xb @ (Wq|Wk|Wv)] + bias; Q/K row-major, V -> VT
__global__ __launch_bounds__(256) void k_gemm_qkv(
    const u16* __restrict__ A, const u16* __restrict__ BT,
    u16* __restrict__ QK, u16* __restrict__ VT,
    const float* __restrict__ biasf)
{
  const int m0 = blockIdx.y * 128;
  // VT batch base: rows of a 128-tile share one batch (2048 % 128 == 0)
  u16* vtb = VT + (size_t)(m0 >> 11) * EMB * SEQ;
  gemm_core<4>(A, EMB, BT, EMB, QK, LDQK, vtb, biasf, nullptr, 1.0f, EMB,
               m0, blockIdx.x * 128);
}

// output projection: d_out = O @ Wo + bo (dtype per flag)
__global__ __launch_bounds__(256) void k_gemm_out(
    const u16* __restrict__ A, const u16* __restrict__ BT,
    void* __restrict__ C, const float* __restrict__ biasf,
    const int* __restrict__ of32)
{
  gemm_core<0>(A, EMB, BT, EMB, C, EMB, nullptr, biasf, of32, 1.0f, EMB,
               blockIdx.y * 128, blockIdx.x * 128);
}

// S[z] = Q[b] @ K[b]^T * scale  (f16 out, pitch 2048 u16)
__global__ __launch_bounds__(256) void k_gemm_scores(
    const u16* __restrict__ QK, u16* __restrict__ S, int b0)
{
  const int b = b0 + blockIdx.z;
  const u16* base = QK + (size_t)b * SEQ * LDQK;
  gemm_core<3>(base, LDQK,              // Q
               base + EMB, LDQK,        // K
               S + (size_t)blockIdx.z * SEQ * SEQ, SEQ,
               nullptr, nullptr, nullptr,
               0.03608439182435161f /* 1/sqrt(768) */, EMB,
               blockIdx.y * 128, blockIdx.x * 128);
}

// O[b] = P[b] @ V[b]  with P bf16 (pitch 2048 u16) and VT[b] = V[b]^T
__global__ __launch_bounds__(256) void k_gemm_pv(
    const u16* __restrict__ P, const u16* __restrict__ VT,
    u16* __restrict__ O, int b0)
{
  const int b = b0 + blockIdx.z;
  gemm_core<2>(P  + (size_t)blockIdx.z * SEQ * SEQ, SEQ,
               VT + (size_t)b * EMB * SEQ, SEQ,
               O  + (size_t)b * SEQ * EMB, EMB,
               nullptr, nullptr, nullptr, 1.0f, SEQ,
               blockIdx.y * 128, blockIdx.x * 128);
}

// row softmax: read f16 row, write bf16 P in place (pitch 2048 u16)
__global__ __launch_bounds__(256) void k_softmax(u16* __restrict__ S)
{
  u16* row = S + ((size_t)blockIdx.y * SEQ + blockIdx.x) * SEQ;
  const int tid = threadIdx.x;

  float v[8];
#pragma unroll
  for (int i = 0; i < 8; ++i)
    v[i] = __half2float(__ushort_as_half(row[tid + i * 256]));

  float mx = v[0];
#pragma unroll
  for (int i = 1; i < 8; ++i) mx = fmaxf(mx, v[i]);
#pragma unroll
  for (int off = 32; off > 0; off >>= 1) mx = fmaxf(mx, __shfl_down(mx, off));
  __shared__ float red[4], red2[4];
  if ((tid & 63) == 0) red[tid >> 6] = mx;
  __syncthreads();
  mx = fmaxf(fmaxf(red[0], red[1]), fmaxf(red[2], red[3]));

  float s = 0.0f;
#pragma unroll
  for (int i = 0; i < 8; ++i) { v[i] = __expf(v[i] - mx); s += v[i]; }
#pragma unroll
  for (int off = 32; off > 0; off >>= 1) s += __shfl_down(s, off);
  if ((tid & 63) == 0) red2[tid >> 6] = s;
  __syncthreads();
  s = red2[0] + red2[1] + red2[2] + red2[3];
  const float inv = 1.0f / s;
#pragma unroll
  for (int i = 0; i < 8; ++i) row[tid + i * 256] = f2bf(v[i] * inv);
}

// ---- host launch ---------------------------------------------------------

extern "C" void kernel_launch(void* const* d_in, const int* in_sizes, int n_in,
                              void* d_out, int out_size, void* d_ws, size_t ws_size,
                              hipStream_t stream)
{
  (void)in_sizes; (void)n_in; (void)out_size;
  const void* x  = d_in[0];
  const void* Wq = d_in[1];
  const void* bq = d_in[2];
  const void* Wk = d_in[3];
  const void* bk = d_in[4];
  const void* Wv = d_in[5];
  const void* bv = d_in[6];
  const void* Wo = d_in[7];
  const void* bo = d_in[8];

  char* ws = (char*)d_ws;
  size_t off = 0;
  auto alloc = [&](size_t bytes) -> void* {
    void* p = ws + off;
    off += (bytes + 255) & ~(size_t)255;
    return p;
  };
  int*   flag  = (int*)alloc(256);
  u16*   xb    = (u16*)alloc((size_t)NB * SEQ * EMB * 2);       // 25.2 MB
  u16*   QK    = (u16*)alloc((size_t)NB * SEQ * LDQK * 2);      // 50.3 MB
  u16*   VT    = (u16*)alloc((size_t)NB * EMB * SEQ * 2);       // 25.2 MB
  u16*   O     = (u16*)alloc((size_t)NB * SEQ * EMB * 2);       // 25.2 MB
  u16*   WT    = (u16*)alloc((size_t)4 * EMB * EMB * 2);        //  4.7 MB
  float* biasf = (float*)alloc((size_t)4 * EMB * 4);
  u16*   S     = (u16*)(ws + off);                              // f16/bf16
  size_t rem   = (ws_size > off) ? ws_size - off : 0;

  int GB = 8;  // batches per S-group; shrink if workspace is tight
  while (GB > 1 && (size_t)GB * ((size_t)SEQ * SEQ * 2) > rem) GB >>= 1;

  // 0. dtype detect + bias conversion, then input normalization to bf16
  k_detect_bias<<<1, 256, 0, stream>>>((const u16*)x, flag, bq, bk, bv, bo,
                                       biasf);
  const int n4 = NB * SEQ * EMB / 4;
  k_convert_x<<<(n4 + 255) / 256, 256, 0, stream>>>(x, xb, flag, n4);
  k_transpose_w<<<dim3(EMB / 32, EMB / 32, 4), dim3(32, 8), 0, stream>>>(
      Wq, Wk, Wv, Wo, WT, flag);

  // 1. fused QKV projection (M=16384, N=2304, K=768); V lands transposed
  k_gemm_qkv<<<dim3(18, 128), 256, 0, stream>>>(xb, WT, QK, VT, biasf);

  // 2. attention per batch-group
  for (int g = 0; g < NB; g += GB) {
    k_gemm_scores<<<dim3(16, 16, GB), 256, 0, stream>>>(QK, S, g);
    k_softmax<<<dim3(SEQ, GB), 256, 0, stream>>>(S);
    k_gemm_pv<<<dim3(6, 16, GB), 256, 0, stream>>>(S, VT, O, g);
  }

  // 3. output projection (dtype of d_out per flag)
  k_gemm_out<<<dim3(6, 128), 256, 0, stream>>>(O, WT + 3 * EMB * EMB, d_out,
                                               biasf + 3 * EMB, flag);
}

// Round 6
// 424.113 us; speedup vs baseline: 1.1745x; 1.0409x over previous
//
#include <hip/hip_runtime.h>
#include <hip/hip_fp16.h>
#include <stdint.h>

typedef unsigned short u16;
typedef __attribute__((ext_vector_type(8))) __bf16 bf16x8;
typedef __attribute__((ext_vector_type(4))) float f32x4;

#define SEQ 2048
#define EMB 768
#define NB  8
#define LDQK (2 * EMB)    // 1536: row pitch of fused Q|K buffer

__device__ __forceinline__ u16 f2bf(float f) {
  union { float f; uint32_t u; } a; a.f = f;
  uint32_t r = a.u + 0x7fffu + ((a.u >> 16) & 1u);
  return (u16)(r >> 16);
}
__device__ __forceinline__ float bf2f(u16 h) {
  union { uint32_t u; float f; } a; a.u = ((uint32_t)h) << 16;
  return a.f;
}

// ---------------------------------------------------------------------------
// dtype detect (1 = fp32 inputs) + bias conversion fused.
// ---------------------------------------------------------------------------
__global__ __launch_bounds__(256) void k_detect_bias(
    const u16* __restrict__ x, int* __restrict__ flag,
    const void* __restrict__ b0, const void* __restrict__ b1,
    const void* __restrict__ b2, const void* __restrict__ b3,
    float* __restrict__ biasf)
{
  const int tid = threadIdx.x;
  int bad = 0;
#pragma unroll
  for (int i = 0; i < 4; ++i) {
    const u16 h = x[(tid * 4 + i) * 2];
    const int e = (h >> 7) & 0xFF;
    bad += (e >= 160 && e <= 254) ? 1 : 0;
  }
#pragma unroll
  for (int off = 32; off > 0; off >>= 1) bad += __shfl_down(bad, off);
  __shared__ int cnt[4];
  __shared__ int sflag;
  if ((tid & 63) == 0) cnt[tid >> 6] = bad;
  __syncthreads();
  if (tid == 0) {
    const int f = (cnt[0] + cnt[1] + cnt[2] + cnt[3] > 200) ? 1 : 0;
    sflag = f;
    *flag = f;
  }
  __syncthreads();
  const int f32 = sflag;
#pragma unroll
  for (int z = 0; z < 4; ++z) {
    const void* src = (z == 0) ? b0 : (z == 1) ? b1 : (z == 2) ? b2 : b3;
#pragma unroll
    for (int i = 0; i < 3; ++i) {
      const int j = tid + i * 256;
      biasf[z * EMB + j] = f32 ? ((const float*)src)[j]
                               : bf2f(((const u16*)src)[j]);
    }
  }
}

__global__ __launch_bounds__(256) void k_convert_x(
    const void* __restrict__ src, u16* __restrict__ dst,
    const int* __restrict__ flag, int n4)
{
  const int i = blockIdx.x * 256 + threadIdx.x;
  if (i >= n4) return;
  if (*flag) {
    const float4 f = ((const float4*)src)[i];
    ushort4 o;
    o.x = f2bf(f.x); o.y = f2bf(f.y); o.z = f2bf(f.z); o.w = f2bf(f.w);
    ((ushort4*)dst)[i] = o;
  } else {
    ((ushort4*)dst)[i] = ((const ushort4*)src)[i];
  }
}

// weights: convert + transpose -> WT (bf16). Rows 0..1535 = Wq^T|Wk^T,
// rows 1536..2303 = Wv^T, rows 2304..3071 = Wo^T.
__global__ __launch_bounds__(256) void k_transpose_w(
    const void* __restrict__ W0, const void* __restrict__ W1,
    const void* __restrict__ W2, const void* __restrict__ W3,
    u16* __restrict__ WT, const int* __restrict__ flag)
{
  __shared__ u16 t[32][33];
  const int z = blockIdx.z;
  const void* in = (z == 0) ? W0 : (z == 1) ? W1 : (z == 2) ? W2 : W3;
  u16* out = WT + (size_t)z * EMB * EMB;
  const int c0 = blockIdx.x * 32, r0 = blockIdx.y * 32;
  const int tx = threadIdx.x, ty = threadIdx.y;
  const int f32 = *flag;
#pragma unroll
  for (int i = 0; i < 4; ++i) {
    const size_t idx = (size_t)(r0 + ty + i * 8) * EMB + c0 + tx;
    t[ty + i * 8][tx] = f32 ? f2bf(((const float*)in)[idx])
                            : ((const u16*)in)[idx];
  }
  __syncthreads();
#pragma unroll
  for (int i = 0; i < 4; ++i)
    out[(size_t)(c0 + ty + i * 8) * EMB + r0 + tx] = t[tx][ty + i * 8];
}

// ---------------------------------------------------------------------------
// 128x128 MFMA GEMM tile: C[m,n] = sum_k A[m,k] * BT[n,k]
// 256 threads = 4 waves, each 64x64 (4x4 MFMA 16x16x32 tiles). BK=32.
// Staging: async global_load_lds width=16 (m97 structure).
// EPI: 0 = col-bias add (bf16/fp32 out per of32); 2 = bf16 out;
//      3 = f16 out * scale; 5 = row-bias add, bf16 out
// ---------------------------------------------------------------------------
template <int EPI>
__device__ __forceinline__ void gemm_core(
    const u16* __restrict__ A, int lda,
    const u16* __restrict__ BT, int ldbt,
    void* __restrict__ Cp, int ldc,
    const float* __restrict__ biasf, const int* __restrict__ of32,
    float scale, int K, int m0, int n0)
{
  __shared__ __align__(16) u16 As[128 * 32];
  __shared__ __align__(16) u16 Bs[128 * 32];
  const int tid  = threadIdx.x;
  const int lane = tid & 63;
  const int wave = tid >> 6;
  const int wr   = (wave >> 1) * 64;
  const int wc   = (wave & 1) * 64;
  const int lrow = lane & 15;
  const int quad = lane >> 4;

  f32x4 acc[4][4];
#pragma unroll
  for (int i = 0; i < 4; ++i)
#pragma unroll
    for (int j = 0; j < 4; ++j)
#pragma unroll
      for (int r = 0; r < 4; ++r) acc[i][j][r] = 0.0f;

  for (int kt = 0; kt < K; kt += 32) {
    // 512 16B chunks per buffer; chunk c -> row c>>2, k-seg c&3.
    // LDS dst is wave-uniform base; HW scatters lane l at base + l*16B.
#pragma unroll
    for (int i = 0; i < 2; ++i) {
      const int c = wave * 128 + i * 64 + lane;
      const int r = c >> 2, s = c & 3;
      const u16* ga = A  + (size_t)(m0 + r) * lda  + kt + s * 8;
      const u16* gb = BT + (size_t)(n0 + r) * ldbt + kt + s * 8;
      u16* la = As + (size_t)(wave * 128 + i * 64) * 8;
      u16* lb = Bs + (size_t)(wave * 128 + i * 64) * 8;
      __builtin_amdgcn_global_load_lds(
          (const __attribute__((address_space(1))) void*)ga,
          (__attribute__((address_space(3))) void*)la, 16, 0, 0);
      __builtin_amdgcn_global_load_lds(
          (const __attribute__((address_space(1))) void*)gb,
          (__attribute__((address_space(3))) void*)lb, 16, 0, 0);
    }
    __syncthreads();  // drains vmcnt: LDS tiles filled

    bf16x8 af[4], bfr[4];
#pragma unroll
    for (int i = 0; i < 4; ++i)
      af[i] = *(const bf16x8*)(As + (wr + i * 16 + lrow) * 32 + quad * 8);
#pragma unroll
    for (int j = 0; j < 4; ++j)
      bfr[j] = *(const bf16x8*)(Bs + (wc + j * 16 + lrow) * 32 + quad * 8);

#pragma unroll
    for (int i = 0; i < 4; ++i)
#pragma unroll
      for (int j = 0; j < 4; ++j)
        acc[i][j] = __builtin_amdgcn_mfma_f32_16x16x32_bf16(af[i], bfr[j],
                                                            acc[i][j], 0, 0, 0);
    __syncthreads();  // ds_reads done before next iter overwrites LDS
  }

  // epilogue: C/D layout col=lane&15, row=quad*4+reg
  if (EPI == 3) {
    u16* C = (u16*)Cp;
#pragma unroll
    for (int i = 0; i < 4; ++i)
#pragma unroll
      for (int j = 0; j < 4; ++j)
#pragma unroll
        for (int r = 0; r < 4; ++r) {
          const int row = m0 + wr + i * 16 + quad * 4 + r;
          const int col = n0 + wc + j * 16 + lrow;
          C[(size_t)row * ldc + col] =
              __half_as_ushort(__float2half(acc[i][j][r] * scale));
        }
  } else if (EPI == 2) {
    u16* C = (u16*)Cp;
#pragma unroll
    for (int i = 0; i < 4; ++i)
#pragma unroll
      for (int j = 0; j < 4; ++j)
#pragma unroll
        for (int r = 0; r < 4; ++r) {
          const int row = m0 + wr + i * 16 + quad * 4 + r;
          const int col = n0 + wc + j * 16 + lrow;
          C[(size_t)row * ldc + col] = f2bf(acc[i][j][r]);
        }
  } else if (EPI == 5) {
    // per-row bias (bias indexed by m), bf16 out
    u16* C = (u16*)Cp;
#pragma unroll
    for (int i = 0; i < 4; ++i)
#pragma unroll
      for (int r = 0; r < 4; ++r) {
        const int row = m0 + wr + i * 16 + quad * 4 + r;
        const float bv = biasf[row];
#pragma unroll
        for (int j = 0; j < 4; ++j) {
          const int col = n0 + wc + j * 16 + lrow;
          C[(size_t)row * ldc + col] = f2bf(acc[i][j][r] + bv);
        }
      }
  } else {  // EPI == 0: per-col bias
    float bv[4];
#pragma unroll
    for (int j = 0; j < 4; ++j) bv[j] = biasf[n0 + wc + j * 16 + lrow];
    const bool f32out = (of32 != nullptr) && (*of32 != 0);
    if (f32out) {
      float* C = (float*)Cp;
#pragma unroll
      for (int i = 0; i < 4; ++i)
#pragma unroll
        for (int j = 0; j < 4; ++j)
#pragma unroll
          for (int r = 0; r < 4; ++r) {
            const int row = m0 + wr + i * 16 + quad * 4 + r;
            const int col = n0 + wc + j * 16 + lrow;
            C[(size_t)row * ldc + col] = acc[i][j][r] + bv[j];
          }
    } else {
      u16* C = (u16*)Cp;
#pragma unroll
      for (int i = 0; i < 4; ++i)
#pragma unroll
        for (int j = 0; j < 4; ++j)
#pragma unroll
          for (int r = 0; r < 4; ++r) {
            const int row = m0 + wr + i * 16 + quad * 4 + r;
            const int col = n0 + wc + j * 16 + lrow;
            C[(size_t)row * ldc + col] = f2bf(acc[i][j][r] + bv[j]);
          }
    }
  }
}

// ---- GEMM kernels --------------------------------------------------------

// Q|K projection: QK[16384][1536] = xb @ (Wq|Wk) + (bq|bk)
__global__ __launch_bounds__(256) void k_gemm_qk(
    const u16* __restrict__ A, const u16* __restrict__ BT,
    u16* __restrict__ QK, const float* __restrict__ biasf)
{
  gemm_core<0>(A, EMB, BT, EMB, QK, LDQK, biasf, nullptr, 1.0f, EMB,
               blockIdx.y * 128, blockIdx.x * 128);
}

// V^T projection, direct: VT[b][v][seq] = sum_k WvT[v,k] * x[b][seq,k] + bv[v]
__global__ __launch_bounds__(256) void k_gemm_vt(
    const u16* __restrict__ WvT, const u16* __restrict__ xb,
    u16* __restrict__ VT, const float* __restrict__ biasv)
{
  const int b = blockIdx.z;
  gemm_core<5>(WvT, EMB,
               xb + (size_t)b * SEQ * EMB, EMB,
               VT + (size_t)b * EMB * SEQ, SEQ,
               biasv, nullptr, 1.0f, EMB,
               blockIdx.y * 128, blockIdx.x * 128);
}

// output projection: d_out = O @ Wo + bo (dtype per flag)
__global__ __launch_bounds__(256) void k_gemm_out(
    const u16* __restrict__ A, const u16* __restrict__ BT,
    void* __restrict__ C, const float* __restrict__ biasf,
    const int* __restrict__ of32)
{
  gemm_core<0>(A, EMB, BT, EMB, C, EMB, biasf, of32, 1.0f, EMB,
               blockIdx.y * 128, blockIdx.x * 128);
}

// S[z] = Q[b] @ K[b]^T * scale  (f16 out, pitch 2048 u16)
__global__ __launch_bounds__(256) void k_gemm_scores(
    const u16* __restrict__ QK, u16* __restrict__ S, int b0)
{
  const int b = b0 + blockIdx.z;
  const u16* base = QK + (size_t)b * SEQ * LDQK;
  gemm_core<3>(base, LDQK,              // Q
               base + EMB, LDQK,        // K
               S + (size_t)blockIdx.z * SEQ * SEQ, SEQ,
               nullptr, nullptr,
               0.03608439182435161f /* 1/sqrt(768) */, EMB,
               blockIdx.y * 128, blockIdx.x * 128);
}

// O[b] = P[b] @ V[b]  with P bf16 (pitch 2048 u16) and VT[b] = V[b]^T
__global__ __launch_bounds__(256) void k_gemm_pv(
    const u16* __restrict__ P, const u16* __restrict__ VT,
    u16* __restrict__ O, int b0)
{
  const int b = b0 + blockIdx.z;
  gemm_core<2>(P  + (size_t)blockIdx.z * SEQ * SEQ, SEQ,
               VT + (size_t)b * EMB * SEQ, SEQ,
               O  + (size_t)b * SEQ * EMB, EMB,
               nullptr, nullptr, 1.0f, SEQ,
               blockIdx.y * 128, blockIdx.x * 128);
}

// row softmax: read f16 row, write bf16 in place. 16B/lane vectorized:
// thread t owns elements [t*8, t*8+8).
__global__ __launch_bounds__(256) void k_softmax(u16* __restrict__ S)
{
  u16* row = S + ((size_t)blockIdx.y * SEQ + blockIdx.x) * SEQ;
  const int tid = threadIdx.x;

  uint4 raw = *(const uint4*)(row + tid * 8);
  const u16* h = (const u16*)&raw;
  float v[8];
#pragma unroll
  for (int i = 0; i < 8; ++i) v[i] = __half2float(__ushort_as_half(h[i]));

  float mx = v[0];
#pragma unroll
  for (int i = 1; i < 8; ++i) mx = fmaxf(mx, v[i]);
#pragma unroll
  for (int off = 32; off > 0; off >>= 1) mx = fmaxf(mx, __shfl_down(mx, off));
  __shared__ float red[4], red2[4];
  if ((tid & 63) == 0) red[tid >> 6] = mx;
  __syncthreads();
  mx = fmaxf(fmaxf(red[0], red[1]), fmaxf(red[2], red[3]));

  float s = 0.0f;
#pragma unroll
  for (int i = 0; i < 8; ++i) { v[i] = __expf(v[i] - mx); s += v[i]; }
#pragma unroll
  for (int off = 32; off > 0; off >>= 1) s += __shfl_down(s, off);
  if ((tid & 63) == 0) red2[tid >> 6] = s;
  __syncthreads();
  s = red2[0] + red2[1] + red2[2] + red2[3];
  const float inv = 1.0f / s;

  uint4 outv;
  u16* o = (u16*)&outv;
#pragma unroll
  for (int i = 0; i < 8; ++i) o[i] = f2bf(v[i] * inv);
  *(uint4*)(row + tid * 8) = outv;
}

// ---- host launch ---------------------------------------------------------

extern "C" void kernel_launch(void* const* d_in, const int* in_sizes, int n_in,
                              void* d_out, int out_size, void* d_ws, size_t ws_size,
                              hipStream_t stream)
{
  (void)in_sizes; (void)n_in; (void)out_size;
  const void* x  = d_in[0];
  const void* Wq = d_in[1];
  const void* bq = d_in[2];
  const void* Wk = d_in[3];
  const void* bk = d_in[4];
  const void* Wv = d_in[5];
  const void* bv = d_in[6];
  const void* Wo = d_in[7];
  const void* bo = d_in[8];

  char* ws = (char*)d_ws;
  size_t off = 0;
  auto alloc = [&](size_t bytes) -> void* {
    void* p = ws + off;
    off += (bytes + 255) & ~(size_t)255;
    return p;
  };
  int*   flag  = (int*)alloc(256);
  u16*   xb    = (u16*)alloc((size_t)NB * SEQ * EMB * 2);       // 25.2 MB
  u16*   QK    = (u16*)alloc((size_t)NB * SEQ * LDQK * 2);      // 50.3 MB
  u16*   VT    = (u16*)alloc((size_t)NB * EMB * SEQ * 2);       // 25.2 MB
  u16*   O     = (u16*)alloc((size_t)NB * SEQ * EMB * 2);       // 25.2 MB
  u16*   WT    = (u16*)alloc((size_t)4 * EMB * EMB * 2);        //  4.7 MB
  float* biasf = (float*)alloc((size_t)4 * EMB * 4);
  u16*   S     = (u16*)(ws + off);                              // f16/bf16
  size_t rem   = (ws_size > off) ? ws_size - off : 0;

  int GB = 8;  // batches per S-group; shrink if workspace is tight
  while (GB > 1 && (size_t)GB * ((size_t)SEQ * SEQ * 2) > rem) GB >>= 1;

  // 0. dtype detect + bias conversion, then input normalization to bf16
  k_detect_bias<<<1, 256, 0, stream>>>((const u16*)x, flag, bq, bk, bv, bo,
                                       biasf);
  const int n4 = NB * SEQ * EMB / 4;
  k_convert_x<<<(n4 + 255) / 256, 256, 0, stream>>>(x, xb, flag, n4);
  k_transpose_w<<<dim3(EMB / 32, EMB / 32, 4), dim3(32, 8), 0, stream>>>(
      Wq, Wk, Wv, Wo, WT, flag);

  // 1a. Q|K projection (M=16384, N=1536, K=768)
  k_gemm_qk<<<dim3(12, 128), 256, 0, stream>>>(xb, WT, QK, biasf);
  // 1b. V^T projection, direct (per batch: M=768(v), N=2048(seq), K=768)
  k_gemm_vt<<<dim3(16, 6, NB), 256, 0, stream>>>(
      WT + (size_t)2 * EMB * EMB, xb, VT, biasf + 2 * EMB);

  // 2. attention per batch-group
  for (int g = 0; g < NB; g += GB) {
    k_gemm_scores<<<dim3(16, 16, GB), 256, 0, stream>>>(QK, S, g);
    k_softmax<<<dim3(SEQ, GB), 256, 0, stream>>>(S);
    k_gemm_pv<<<dim3(6, 16, GB), 256, 0, stream>>>(S, VT, O, g);
  }

  // 3. output projection (dtype of d_out per flag)
  k_gemm_out<<<dim3(6, 128), 256, 0, stream>>>(O, WT + 3 * EMB * EMB, d_out,
                                               biasf + 3 * EMB, flag);
}